// Round 6
// baseline (206.921 us; speedup 1.0000x reference)
//
#include <hip/hip_runtime.h>

#define D 64
#define H 16
#define PPT 4   // positions per thread

typedef float  f32x2 __attribute__((ext_vector_type(2)));
typedef float  f32x4 __attribute__((ext_vector_type(4)));

// 32 consecutive threads = one position; each thread owns a fixed 2-dim slice
// (d2) of the 64-wide output. Round-6 change: halve the per-thread register
// state (w2 slice 64->32 regs, gather batch 32->8 regs) and pin occupancy
// with __launch_bounds__(256,4) (VGPR cap 128, 16 waves/CU). Round-5's ~58us
// kernel is theorized occupancy-starved (~200 VGPR demand, no min-wave bound
// -> ~2/SIMD; the input->gather->store chains can't pipeline). Weights stay
// register-resident (round 2 proved per-position LDS reads saturate the DS
// pipe at ~75us). Branchless select; plain f32x2 stores (wave = 512B
// contiguous; the 6.6TB/s fill kernel stores only 4B/lane, so 8B is ample).
__global__ __launch_bounds__(256, 4) void Embedder_kernel(
    const float* __restrict__ input_ids,
    const int*   __restrict__ type_mask,
    const float* __restrict__ emb,
    const float* __restrict__ w1,
    const float* __restrict__ b1,
    const float* __restrict__ w2,
    const float* __restrict__ b2,
    float*       __restrict__ out,
    int npos)
{
    const int tid = threadIdx.x;
    const int gid = blockIdx.x * 256 + tid;
    const int d2 = (gid & 31) * 2;        // fixed 2-dim output slice
    const int pbase = gid >> 5;           // first position
    const int pstep = npos / PPT;         // stride between this thread's positions

    // ---- issue all input loads first (head of the longest dep chain) ----
    float xv[PPT]; int mv[PPT];
    #pragma unroll
    for (int k = 0; k < PPT; ++k) {
        const int p = pbase + k * pstep;
        xv[k] = input_ids[p];
        mv[k] = type_mask[p];
    }

    // ---- weight staging into registers (independent; overlaps the above) ----
    float w2s[2][H];                      // w2s[r][j] = w2[(d2+r)*H + j]
    #pragma unroll
    for (int r = 0; r < 2; ++r) {
        #pragma unroll
        for (int c = 0; c < 4; ++c) {
            const f32x4 t = *reinterpret_cast<const f32x4*>(&w2[(d2 + r) * H + 4 * c]);
            w2s[r][4*c+0] = t.x; w2s[r][4*c+1] = t.y;
            w2s[r][4*c+2] = t.z; w2s[r][4*c+3] = t.w;
        }
    }
    float w1r[H], b1r[H];
    #pragma unroll
    for (int c = 0; c < 4; ++c) {
        const f32x4 tw = *reinterpret_cast<const f32x4*>(&w1[4*c]);
        const f32x4 tb = *reinterpret_cast<const f32x4*>(&b1[4*c]);
        w1r[4*c+0] = tw.x; w1r[4*c+1] = tw.y; w1r[4*c+2] = tw.z; w1r[4*c+3] = tw.w;
        b1r[4*c+0] = tb.x; b1r[4*c+1] = tb.y; b1r[4*c+2] = tb.z; b1r[4*c+3] = tb.w;
    }
    const f32x2 b2s = *reinterpret_cast<const f32x2*>(&b2[d2]);

    // ---- all gathers (stay in flight under the MLP below) ----
    f32x2 g[PPT];
    #pragma unroll
    for (int k = 0; k < PPT; ++k) {
        const int id = mv[k] ? (int)xv[k] : 0;   // row 0 is the zero PAD row
        g[k] = *reinterpret_cast<const f32x2*>(&emb[(size_t)id * D + d2]);
    }

    // ---- MLP + select + store per position ----
    #pragma unroll
    for (int k = 0; k < PPT; ++k) {
        f32x2 a = b2s;
        #pragma unroll
        for (int j = 0; j < H; ++j) {
            const float h = fmaxf(fmaf(xv[k], w1r[j], b1r[j]), 0.0f);
            a.x = fmaf(h, w2s[0][j], a.x);
            a.y = fmaf(h, w2s[1][j], a.y);
        }
        f32x2 r;
        r.x = mv[k] ? g[k].x : a.x;
        r.y = mv[k] ? g[k].y : a.y;
        *reinterpret_cast<f32x2*>(&out[(size_t)(pbase + k * pstep) * D + d2]) = r;
    }
}

extern "C" void kernel_launch(void* const* d_in, const int* in_sizes, int n_in,
                              void* d_out, int out_size, void* d_ws, size_t ws_size,
                              hipStream_t stream) {
    const float* input_ids = (const float*)d_in[0];
    const int*   type_mask = (const int*)d_in[1];
    const float* emb       = (const float*)d_in[2];
    const float* w1        = (const float*)d_in[3];
    const float* b1        = (const float*)d_in[4];
    const float* w2        = (const float*)d_in[5];
    const float* b2        = (const float*)d_in[6];
    float*       out       = (float*)d_out;

    const int npos = in_sizes[0];                   // B*S = 524288
    const long long T = (long long)npos * 32 / PPT; // 4,194,304 threads
    const int blocks = (int)((T + 255) / 256);      // 16384 blocks

    Embedder_kernel<<<blocks, 256, 0, stream>>>(
        input_ids, type_mask, emb, w1, b1, w2, b2, out, npos);
}